// Round 1
// baseline (585.830 us; speedup 1.0000x reference)
//
#include <hip/hip_runtime.h>
#include <math.h>

#define PI2 6.2831853071795864769f

// Problem constants: B=16, C_in=C_out=64, H=W=256, MH=8, MW=12
// NIMG = B*C = 1024 images each direction.

// ---------------------------------------------------------------------------
// K1: forward. For each input image (b,i):
//   S[ky][w]  = sum_h x[h][w] * e^{-2pi i ky h/256}   (ky<8)   [reg-accumulated]
//   Xm[ky][kx]= (1/256) * sum_w S[ky][w] * e^{-2pi i kx w/256} (kx<12) [from LDS]
// One block (4 waves) per image; wave wv covers h in [wv*64, wv*64+64).
// Lane l owns w = 4l..4l+3 (float4 coalesced row loads).
// ---------------------------------------------------------------------------
__global__ __launch_bounds__(256) void k1_fwd(const float* __restrict__ x,
                                              float* __restrict__ Xm) {
  __shared__ float lds[2][4096];  // [buf][(ky*256+w)*2 + {re,im}]  32 KB
  const int img  = blockIdx.x;
  const int wv   = threadIdx.x >> 6;
  const int lane = threadIdx.x & 63;
  const int h0   = wv * 64;

  // Twiddle state: cur = e^{i*2pi*ky*h/256} stored as (c,s); apply with conj.
  float cr[8], sr[8], Cs[8], Ss[8];
#pragma unroll
  for (int ky = 0; ky < 8; ++ky) {
    float th0 = PI2 * (float)((ky * h0) & 255) * (1.0f / 256.0f);
    __sincosf(th0, &sr[ky], &cr[ky]);
    float dth = PI2 * (float)ky * (1.0f / 256.0f);
    __sincosf(dth, &Ss[ky], &Cs[ky]);
  }

  float aR[8][4], aI[8][4];
#pragma unroll
  for (int ky = 0; ky < 8; ++ky)
#pragma unroll
    for (int j = 0; j < 4; ++j) { aR[ky][j] = 0.0f; aI[ky][j] = 0.0f; }

  const float* xp = x + (size_t)img * 65536 + (size_t)h0 * 256 + lane * 4;
#pragma unroll 4
  for (int it = 0; it < 64; ++it) {
    float4 xv = *(const float4*)xp;
    xp += 256;
#pragma unroll
    for (int ky = 0; ky < 8; ++ky) {
      float c = cr[ky], s = sr[ky];
      aR[ky][0] = fmaf(xv.x,  c, aR[ky][0]);  aI[ky][0] = fmaf(xv.x, -s, aI[ky][0]);
      aR[ky][1] = fmaf(xv.y,  c, aR[ky][1]);  aI[ky][1] = fmaf(xv.y, -s, aI[ky][1]);
      aR[ky][2] = fmaf(xv.z,  c, aR[ky][2]);  aI[ky][2] = fmaf(xv.z, -s, aI[ky][2]);
      aR[ky][3] = fmaf(xv.w,  c, aR[ky][3]);  aI[ky][3] = fmaf(xv.w, -s, aI[ky][3]);
      cr[ky] = fmaf(c, Cs[ky], -s * Ss[ky]);   // rotate by e^{i*2pi*ky/256}
      sr[ky] = fmaf(s, Cs[ky],  c * Ss[ky]);
    }
  }

  // Combine 4 wave-partials: waves 0,1 store; waves 2,3 add; then buf0+=buf1.
  if (wv < 2) {
#pragma unroll
    for (int ky = 0; ky < 8; ++ky)
#pragma unroll
      for (int j = 0; j < 4; ++j) {
        int p = (ky * 256 + lane * 4 + j) * 2;
        lds[wv][p] = aR[ky][j];
        lds[wv][p + 1] = aI[ky][j];
      }
  }
  __syncthreads();
  if (wv >= 2) {
#pragma unroll
    for (int ky = 0; ky < 8; ++ky)
#pragma unroll
      for (int j = 0; j < 4; ++j) {
        int p = (ky * 256 + lane * 4 + j) * 2;
        lds[wv - 2][p] += aR[ky][j];
        lds[wv - 2][p + 1] += aI[ky][j];
      }
  }
  __syncthreads();
  for (int f = threadIdx.x; f < 4096; f += 256) lds[0][f] += lds[1][f];
  __syncthreads();

  // w-DFT: 96 threads, one (ky,kx) each; serial over 256 w from LDS.
  if (threadIdx.x < 96) {
    int ky = threadIdx.x / 12, kx = threadIdx.x % 12;
    float Cw, Sw;
    __sincosf(PI2 * (float)kx * (1.0f / 256.0f), &Sw, &Cw);
    float c = 1.0f, s = 0.0f, Xr = 0.0f, Xi = 0.0f;
    const float* base = &lds[0][ky * 512];
    for (int w = 0; w < 256; ++w) {
      float Sre = base[w * 2], Sim = base[w * 2 + 1];
      // multiply by e^{-i th} = (c, -s)
      Xr += Sre * c + Sim * s;
      Xi += Sim * c - Sre * s;
      float nc = fmaf(c, Cw, -s * Sw);
      s = fmaf(s, Cw, c * Sw);
      c = nc;
    }
    Xm[((size_t)img * 96 + threadIdx.x) * 2]     = Xr * (1.0f / 256.0f);
    Xm[((size_t)img * 96 + threadIdx.x) * 2 + 1] = Xi * (1.0f / 256.0f);
  }
}

// ---------------------------------------------------------------------------
// K3: mode mixing. One block per mode position pos = ky*12+kx (96 blocks).
//   Fm[b,o,pos] = sum_i Xm[b,i,pos] * W[i,o,pos]   (complex)
// ---------------------------------------------------------------------------
__global__ __launch_bounds__(256) void k3_mix(const float* __restrict__ Xm,
                                              const float* __restrict__ wt,
                                              float* __restrict__ Fm) {
  __shared__ float Xs[1024 * 2];  // [b*64+i] re,im   8 KB
  __shared__ float Ws[4096 * 2];  // [i*64+o] re,im  32 KB
  const int pos = blockIdx.x;
  for (int idx = threadIdx.x; idx < 1024; idx += 256) {
    Xs[idx * 2]     = Xm[((size_t)idx * 96 + pos) * 2];
    Xs[idx * 2 + 1] = Xm[((size_t)idx * 96 + pos) * 2 + 1];
  }
  for (int idx = threadIdx.x; idx < 4096; idx += 256) {
    Ws[idx * 2]     = wt[((size_t)idx * 96 + pos) * 2];
    Ws[idx * 2 + 1] = wt[((size_t)idx * 96 + pos) * 2 + 1];
  }
  __syncthreads();
  const int b = threadIdx.x >> 4;          // 0..15
  const int og = (threadIdx.x & 15) * 4;   // 0..60
  float ar[4] = {0, 0, 0, 0}, ai[4] = {0, 0, 0, 0};
  for (int i = 0; i < 64; ++i) {
    float xr = Xs[(b * 64 + i) * 2], xi = Xs[(b * 64 + i) * 2 + 1];
#pragma unroll
    for (int r = 0; r < 4; ++r) {
      float wr = Ws[(i * 64 + og + r) * 2], wi = Ws[(i * 64 + og + r) * 2 + 1];
      ar[r] += xr * wr - xi * wi;
      ai[r] += xr * wi + xi * wr;
    }
  }
#pragma unroll
  for (int r = 0; r < 4; ++r) {
    Fm[((size_t)(b * 64 + og + r) * 96 + pos) * 2]     = ar[r];
    Fm[((size_t)(b * 64 + og + r) * 96 + pos) * 2 + 1] = ai[r];
  }
}

// ---------------------------------------------------------------------------
// K4a: inverse H-expansion with alpha/256 folded in.
//   U[img2][h][kx] = (alpha_kx/256) * sum_ky Fm[img2][ky][kx] * e^{+2pi i ky h/256}
// One block per output image img2 = b*64+o; thread = h.
// ---------------------------------------------------------------------------
__global__ __launch_bounds__(256) void k4a_invh(const float* __restrict__ Fm,
                                                float* __restrict__ U) {
  __shared__ float Fs[192];
  const int img2 = blockIdx.x;
  if (threadIdx.x < 192) Fs[threadIdx.x] = Fm[(size_t)img2 * 192 + threadIdx.x];
  __syncthreads();
  const int h = threadIdx.x;
  float cc[8], ss[8];
#pragma unroll
  for (int ky = 0; ky < 8; ++ky) {
    float th = PI2 * (float)((ky * h) & 255) * (1.0f / 256.0f);
    __sincosf(th, &ss[ky], &cc[ky]);
  }
  float4 ov4[6];
  float* ov = (float*)ov4;
#pragma unroll
  for (int kx = 0; kx < 12; ++kx) {
    float Ur = 0.0f, Ui = 0.0f;
#pragma unroll
    for (int ky = 0; ky < 8; ++ky) {
      float Fr = Fs[(ky * 12 + kx) * 2], Fi = Fs[(ky * 12 + kx) * 2 + 1];
      Ur += Fr * cc[ky] - Fi * ss[ky];
      Ui += Fr * ss[ky] + Fi * cc[ky];
    }
    float a = (kx == 0 ? 1.0f : 2.0f) * (1.0f / 256.0f);
    ov[kx * 2] = Ur * a;
    ov[kx * 2 + 1] = Ui * a;
  }
  float4* dst = (float4*)(U + ((size_t)img2 * 256 + h) * 24);
#pragma unroll
  for (int k = 0; k < 6; ++k) dst[k] = ov4[k];
}

// ---------------------------------------------------------------------------
// K4b: inverse W-expansion (real part).
//   out[row][w] = sum_kx Ur[kx]*cos(2pi kx w/256) - Ui[kx]*sin(...)
// Wave per 64 rows; lane l owns w=4l..4l+3; twiddles precomputed per lane.
// ---------------------------------------------------------------------------
__global__ __launch_bounds__(256) void k4b_invw(const float* __restrict__ U,
                                                float* __restrict__ outp) {
  const int wid = blockIdx.x * 4 + (threadIdx.x >> 6);
  const int lane = threadIdx.x & 63;
  float c[12][4], s[12][4];
#pragma unroll
  for (int kx = 0; kx < 12; ++kx)
#pragma unroll
    for (int j = 0; j < 4; ++j) {
      float th = PI2 * (float)((kx * (lane * 4 + j)) & 255) * (1.0f / 256.0f);
      __sincosf(th, &s[kx][j], &c[kx][j]);
    }
  for (int r = 0; r < 64; ++r) {
    const int row = wid * 64 + r;  // row = img2*256 + h
    float4 u4[6];
    const float4* us = (const float4*)(U + (size_t)row * 24);
#pragma unroll
    for (int k = 0; k < 6; ++k) u4[k] = us[k];
    const float* u = (const float*)u4;
    float acc0 = 0, acc1 = 0, acc2 = 0, acc3 = 0;
#pragma unroll
    for (int kx = 0; kx < 12; ++kx) {
      float ur = u[kx * 2], ui = u[kx * 2 + 1];
      acc0 = fmaf(ur, c[kx][0], fmaf(-ui, s[kx][0], acc0));
      acc1 = fmaf(ur, c[kx][1], fmaf(-ui, s[kx][1], acc1));
      acc2 = fmaf(ur, c[kx][2], fmaf(-ui, s[kx][2], acc2));
      acc3 = fmaf(ur, c[kx][3], fmaf(-ui, s[kx][3], acc3));
    }
    float4 o = {acc0, acc1, acc2, acc3};
    *(float4*)(outp + (size_t)row * 256 + lane * 4) = o;
  }
}

extern "C" void kernel_launch(void* const* d_in, const int* in_sizes, int n_in,
                              void* d_out, int out_size, void* d_ws, size_t ws_size,
                              hipStream_t stream) {
  const float* x  = (const float*)d_in[0];   // (16,64,256,256)
  const float* wt = (const float*)d_in[1];   // (64,64,8,12,2)
  float* outp = (float*)d_out;               // (16,64,256,256)

  float* Xm = (float*)d_ws;        // 1024*96*2   = 196608 floats
  float* Fm = Xm + 196608;         // 196608 floats
  float* U  = Fm + 196608;         // 1024*256*12*2 = 6291456 floats
  // total workspace: 27.3 MB

  k1_fwd  <<<1024, 256, 0, stream>>>(x, Xm);
  k3_mix  <<<  96, 256, 0, stream>>>(Xm, wt, Fm);
  k4a_invh<<<1024, 256, 0, stream>>>(Fm, U);
  k4b_invw<<<1024, 256, 0, stream>>>(U, outp);
}

// Round 2
// 542.660 us; speedup vs baseline: 1.0796x; 1.0796x over previous
//
#include <hip/hip_runtime.h>
#include <math.h>

#define PI2 6.2831853071795864769f

// Problem constants: B=16, C_in=C_out=64, H=W=256, MH=8, MW=12
// NIMG = B*C = 1024 images each direction.

// ---------------------------------------------------------------------------
// K1: forward H-DFT then W-DFT for one input image per block.
//   S[ky][w]  = sum_h x[h][w] * e^{-2pi i ky h/256}   (ky<8)
//   Xm[ky][kx]= (1/256) * sum_w S[ky][w] * e^{-2pi i kx w/256} (kx<12)
// Twiddles from an LDS table storing (cos, -sin). h paired with h+128:
//   e^{-i th(ky,h+128)} = (-1)^ky e^{-i th(ky,h)}  -> even ky use (xa+xb),
//   odd ky use (xa-xb); halves the FMA count.
// Wave wv covers h in [wv*32, wv*32+32) (+ the +128 partners).
// Lane l owns w = 4l..4l+3 (float4 coalesced row loads).
// Xm layout: [pos][img] (pos = ky*12+kx) so K3 reads contiguously.
// ---------------------------------------------------------------------------
__global__ __launch_bounds__(256) void k1_fwd(const float* __restrict__ x,
                                              float* __restrict__ Xm) {
  __shared__ float tw[128][16];   // [h][ky*2 + {cos, -sin}]  8 KB
  __shared__ float lds[2][4096];  // [buf][(ky*256+w)*2 + {re,im}]  32 KB
  const int img  = blockIdx.x;
  const int wv   = threadIdx.x >> 6;
  const int lane = threadIdx.x & 63;

  // Fill twiddle table: 128 h x 8 ky, 2 threads per h.
  {
    int h = threadIdx.x >> 1;
    int kyb = (threadIdx.x & 1) * 4;
#pragma unroll
    for (int j = 0; j < 4; ++j) {
      int ky = kyb + j;
      float th = PI2 * (float)((ky * h) & 255) * (1.0f / 256.0f);
      float s_, c_;
      __sincosf(th, &s_, &c_);
      tw[h][ky * 2] = c_;
      tw[h][ky * 2 + 1] = -s_;
    }
  }
  __syncthreads();

  float aR[8][4], aI[8][4];
#pragma unroll
  for (int ky = 0; ky < 8; ++ky)
#pragma unroll
    for (int j = 0; j < 4; ++j) { aR[ky][j] = 0.0f; aI[ky][j] = 0.0f; }

  const float* xa = x + (size_t)img * 65536 + (size_t)(wv * 32) * 256 + lane * 4;
  const float* xb = xa + 128 * 256;
  for (int it = 0; it < 32; ++it) {
    const int h = wv * 32 + it;
    float4 va = *(const float4*)xa;
    float4 vb = *(const float4*)xb;
    xa += 256; xb += 256;
    float p0 = va.x + vb.x, p1 = va.y + vb.y, p2 = va.z + vb.z, p3 = va.w + vb.w;
    float m0 = va.x - vb.x, m1 = va.y - vb.y, m2 = va.z - vb.z, m3 = va.w - vb.w;
#pragma unroll
    for (int ky = 0; ky < 8; ++ky) {
      float c  = tw[h][ky * 2];
      float ns = tw[h][ky * 2 + 1];  // == -sin
      float u0, u1, u2, u3;
      if (ky & 1) { u0 = m0; u1 = m1; u2 = m2; u3 = m3; }
      else        { u0 = p0; u1 = p1; u2 = p2; u3 = p3; }
      aR[ky][0] = fmaf(u0, c, aR[ky][0]);  aI[ky][0] = fmaf(u0, ns, aI[ky][0]);
      aR[ky][1] = fmaf(u1, c, aR[ky][1]);  aI[ky][1] = fmaf(u1, ns, aI[ky][1]);
      aR[ky][2] = fmaf(u2, c, aR[ky][2]);  aI[ky][2] = fmaf(u2, ns, aI[ky][2]);
      aR[ky][3] = fmaf(u3, c, aR[ky][3]);  aI[ky][3] = fmaf(u3, ns, aI[ky][3]);
    }
  }

  // Combine 4 wave-partials: waves 0,1 store; waves 2,3 add; then buf0+=buf1.
  if (wv < 2) {
#pragma unroll
    for (int ky = 0; ky < 8; ++ky)
#pragma unroll
      for (int j = 0; j < 4; ++j) {
        int p = (ky * 256 + lane * 4 + j) * 2;
        lds[wv][p] = aR[ky][j];
        lds[wv][p + 1] = aI[ky][j];
      }
  }
  __syncthreads();
  if (wv >= 2) {
#pragma unroll
    for (int ky = 0; ky < 8; ++ky)
#pragma unroll
      for (int j = 0; j < 4; ++j) {
        int p = (ky * 256 + lane * 4 + j) * 2;
        lds[wv - 2][p] += aR[ky][j];
        lds[wv - 2][p + 1] += aI[ky][j];
      }
  }
  __syncthreads();
  for (int f = threadIdx.x; f < 4096; f += 256) lds[0][f] += lds[1][f];
  __syncthreads();

  // w-DFT: 96 threads, one (ky,kx) each; serial over 256 w from LDS.
  if (threadIdx.x < 96) {
    int ky = threadIdx.x / 12, kx = threadIdx.x % 12;
    float Cw, Sw;
    __sincosf(PI2 * (float)kx * (1.0f / 256.0f), &Sw, &Cw);
    float c = 1.0f, s = 0.0f, Xr = 0.0f, Xi = 0.0f;
    const float* base = &lds[0][ky * 512];
    for (int w = 0; w < 256; ++w) {
      float Sre = base[w * 2], Sim = base[w * 2 + 1];
      Xr += Sre * c + Sim * s;
      Xi += Sim * c - Sre * s;
      float nc = fmaf(c, Cw, -s * Sw);
      s = fmaf(s, Cw, c * Sw);
      c = nc;
    }
    float2 v = { Xr * (1.0f / 256.0f), Xi * (1.0f / 256.0f) };
    ((float2*)Xm)[(size_t)threadIdx.x * 1024 + img] = v;
  }
}

// ---------------------------------------------------------------------------
// K3: mode mixing. One block per mode position pos = ky*12+kx (96 blocks).
//   Fm[b,o,pos] = sum_i Xm[pos][b*64+i] * W[i,o,pos]   (complex)
// Xm layout [pos][img] -> fully contiguous X-stage load.
// Fm layout [img2][pos] (img2 = b*64+o) -> contiguous K4a read.
// ---------------------------------------------------------------------------
__global__ __launch_bounds__(256) void k3_mix(const float* __restrict__ Xm,
                                              const float* __restrict__ wt,
                                              float* __restrict__ Fm) {
  __shared__ float Xs[1024 * 2];  // [img] re,im   8 KB
  __shared__ float Ws[4096 * 2];  // [i*64+o] re,im  32 KB
  const int pos = blockIdx.x;
  for (int idx = threadIdx.x; idx < 2048; idx += 256)
    Xs[idx] = Xm[(size_t)pos * 2048 + idx];
  for (int idx = threadIdx.x; idx < 4096; idx += 256) {
    Ws[idx * 2]     = wt[((size_t)idx * 96 + pos) * 2];
    Ws[idx * 2 + 1] = wt[((size_t)idx * 96 + pos) * 2 + 1];
  }
  __syncthreads();
  const int b = threadIdx.x >> 4;          // 0..15
  const int og = (threadIdx.x & 15) * 4;   // 0..60
  float ar[4] = {0, 0, 0, 0}, ai[4] = {0, 0, 0, 0};
  for (int i = 0; i < 64; ++i) {
    float xr = Xs[(b * 64 + i) * 2], xi = Xs[(b * 64 + i) * 2 + 1];
#pragma unroll
    for (int r = 0; r < 4; ++r) {
      float wr = Ws[(i * 64 + og + r) * 2], wi = Ws[(i * 64 + og + r) * 2 + 1];
      ar[r] += xr * wr - xi * wi;
      ai[r] += xr * wi + xi * wr;
    }
  }
#pragma unroll
  for (int r = 0; r < 4; ++r) {
    Fm[((size_t)(b * 64 + og + r) * 96 + pos) * 2]     = ar[r];
    Fm[((size_t)(b * 64 + og + r) * 96 + pos) * 2 + 1] = ai[r];
  }
}

// ---------------------------------------------------------------------------
// K4a: inverse H-expansion with alpha/256 folded in.
//   U[img2][h][kx] = (alpha_kx/256) * sum_ky Fm[img2][ky][kx] * e^{+2pi i ky h/256}
// One block per output image img2 = b*64+o; thread = h.
// ---------------------------------------------------------------------------
__global__ __launch_bounds__(256) void k4a_invh(const float* __restrict__ Fm,
                                                float* __restrict__ U) {
  __shared__ float Fs[192];
  const int img2 = blockIdx.x;
  if (threadIdx.x < 192) Fs[threadIdx.x] = Fm[(size_t)img2 * 192 + threadIdx.x];
  __syncthreads();
  const int h = threadIdx.x;
  float cc[8], ss[8];
#pragma unroll
  for (int ky = 0; ky < 8; ++ky) {
    float th = PI2 * (float)((ky * h) & 255) * (1.0f / 256.0f);
    __sincosf(th, &ss[ky], &cc[ky]);
  }
  float4 ov4[6];
  float* ov = (float*)ov4;
#pragma unroll
  for (int kx = 0; kx < 12; ++kx) {
    float Ur = 0.0f, Ui = 0.0f;
#pragma unroll
    for (int ky = 0; ky < 8; ++ky) {
      float Fr = Fs[(ky * 12 + kx) * 2], Fi = Fs[(ky * 12 + kx) * 2 + 1];
      Ur += Fr * cc[ky] - Fi * ss[ky];
      Ui += Fr * ss[ky] + Fi * cc[ky];
    }
    float a = (kx == 0 ? 1.0f : 2.0f) * (1.0f / 256.0f);
    ov[kx * 2] = Ur * a;
    ov[kx * 2 + 1] = Ui * a;
  }
  float4* dst = (float4*)(U + ((size_t)img2 * 256 + h) * 24);
#pragma unroll
  for (int k = 0; k < 6; ++k) dst[k] = ov4[k];
}

// ---------------------------------------------------------------------------
// K4b: inverse W-expansion (real part), thread-per-w.
//   out[h][w] = sum_kx Ur[kx]*cos(2pi kx w/256) - Ui[kx]*sin(...)
// One block per img2; 256 threads = one full output row; loop over 256 h.
// Only ~60 VGPRs live -> high occupancy, no spill.
// ---------------------------------------------------------------------------
__global__ __launch_bounds__(256) void k4b_invw(const float* __restrict__ U,
                                                float* __restrict__ outp) {
  const int img2 = blockIdx.x;
  const int w = threadIdx.x;
  float c[12], ns[12];
#pragma unroll
  for (int kx = 0; kx < 12; ++kx) {
    float th = PI2 * (float)((kx * w) & 255) * (1.0f / 256.0f);
    float s_;
    __sincosf(th, &s_, &c[kx]);
    ns[kx] = -s_;
  }
  const float* ub = U + (size_t)img2 * 6144;
  float* ob = outp + (size_t)img2 * 65536 + w;
  for (int h = 0; h < 256; ++h) {
    float4 u4[6];
    const float4* us = (const float4*)(ub + h * 24);
#pragma unroll
    for (int k = 0; k < 6; ++k) u4[k] = us[k];
    const float* u = (const float*)u4;
    float acc = 0.0f;
#pragma unroll
    for (int kx = 0; kx < 12; ++kx)
      acc = fmaf(u[kx * 2], c[kx], fmaf(u[kx * 2 + 1], ns[kx], acc));
    ob[h * 256] = acc;
  }
}

extern "C" void kernel_launch(void* const* d_in, const int* in_sizes, int n_in,
                              void* d_out, int out_size, void* d_ws, size_t ws_size,
                              hipStream_t stream) {
  const float* x  = (const float*)d_in[0];   // (16,64,256,256)
  const float* wt = (const float*)d_in[1];   // (64,64,8,12,2)
  float* outp = (float*)d_out;               // (16,64,256,256)

  float* Xm = (float*)d_ws;        // [96][1024][2]   = 196608 floats
  float* Fm = Xm + 196608;         // [1024][96][2]   = 196608 floats
  float* U  = Fm + 196608;         // [1024][256][24] = 6291456 floats
  // total workspace: 27.3 MB

  k1_fwd  <<<1024, 256, 0, stream>>>(x, Xm);
  k3_mix  <<<  96, 256, 0, stream>>>(Xm, wt, Fm);
  k4a_invh<<<1024, 256, 0, stream>>>(Fm, U);
  k4b_invw<<<1024, 256, 0, stream>>>(U, outp);
}